// Round 8
// baseline (914.380 us; speedup 1.0000x reference)
//
#include <hip/hip_runtime.h>
#include <hip/hip_bf16.h>

#define HH 8
#define DD 64
#define NN 256
#define Q1c 21
#define Q2c 21
#define MM 4096
#define KTOT 2048   // HH*NN

typedef __attribute__((ext_vector_type(4))) int i32x4;
typedef __attribute__((ext_vector_type(16))) int i32x16;

// Kernel 0: pack Z2 (int32 [j][m]) -> Z2t bytes [j/8][m][8] so k_gemm loads
// 8 indices with one dwordx2.
__global__ void k_pack(const int* __restrict__ Z2, unsigned char* __restrict__ Z2t) {
  int jb = blockIdx.x >> 4;                       // 0..31
  int m  = ((blockIdx.x & 15) << 8) + threadIdx.x;
  unsigned lo = 0, hi = 0;
#pragma unroll
  for (int r = 0; r < 4; ++r) lo |= ((unsigned)Z2[(jb*8 + r)*MM + m] & 255u) << (8*r);
#pragma unroll
  for (int r = 0; r < 4; ++r) hi |= ((unsigned)Z2[(jb*8 + 4 + r)*MM + m] & 255u) << (8*r);
  uint2 v; v.x = lo; v.y = hi;
  *reinterpret_cast<uint2*>(Z2t + ((size_t)jb*MM + m)*8) = v;
}

// Kernel 0b: quantize V: sV = max|V|/127; qVt[(a*21+c)*8 + h] = round(V[h][a][c]/sV).
__global__ void k_prep(const float* __restrict__ Vf, unsigned char* __restrict__ qVt,
                       float* __restrict__ sVbuf) {
  __shared__ float red[4];
  int t = threadIdx.x;
  float mx = 0.f;
  for (int x = t; x < HH*Q1c*Q2c; x += 256) mx = fmaxf(mx, fabsf(Vf[x]));
#pragma unroll
  for (int o = 32; o; o >>= 1) mx = fmaxf(mx, __shfl_xor(mx, o));
  if ((t & 63) == 0) red[t >> 6] = mx;
  __syncthreads();
  mx = fmaxf(fmaxf(red[0], red[1]), fmaxf(red[2], red[3]));
  if (t == 0) sVbuf[0] = mx / 127.f;
  float inv = 127.f / mx;
  for (int x = t; x < HH*Q1c*Q2c; x += 256) {
    int h = x / (Q1c*Q2c);
    int rem = x - h*(Q1c*Q2c);
    int a = rem / Q2c, c = rem - a*Q2c;
    int qv = __float2int_rn(Vf[x] * inv);
    qVt[(a*Q2c + c)*8 + h] = (unsigned char)(qv & 255);
  }
}

// Kernel 1: e = Q^T K per head, softmax over j. Writes sf (f32, for k_mmat) and
// qsfF: u8 A-operand pre-fragmented for i8 MFMA with k-order pi(s,lo,d,b):
// j = u*16 + 8*lo + 2*s01(+hf*4) + (d>>1), h = (d&1)*4 + b.
__global__ void k_softmax(const float* __restrict__ Q, const float* __restrict__ K,
                          float* __restrict__ sf, unsigned char* __restrict__ qsfF) {
  int h = blockIdx.x >> 8;
  int i = blockIdx.x & 255;
  int j = threadIdx.x;
  __shared__ float qs[DD];
  __shared__ float red[4];
  if (j < DD) qs[j] = Q[(h*DD + j)*NN + i];
  __syncthreads();
  float e = 0.f;
#pragma unroll
  for (int d = 0; d < DD; ++d) e = fmaf(qs[d], K[(h*DD + d)*NN + j], e);
  float mx = e;
#pragma unroll
  for (int o = 32; o; o >>= 1) mx = fmaxf(mx, __shfl_xor(mx, o));
  if ((j & 63) == 0) red[j >> 6] = mx;
  __syncthreads();
  mx = fmaxf(fmaxf(red[0], red[1]), fmaxf(red[2], red[3]));
  float p = __expf(e - mx);
  float s = p;
#pragma unroll
  for (int o = 32; o; o >>= 1) s += __shfl_xor(s, o);
  __syncthreads();
  if ((j & 63) == 0) red[j >> 6] = s;
  __syncthreads();
  s = red[0] + red[1] + red[2] + red[3];
  p = p / s;
  sf[(h*NN + i)*NN + j] = p;
  // i8 fragment placement
  int u = j >> 4, r8 = j & 15;
  int lo = r8 >> 3, r = r8 & 7;
  int ss = r >> 1, dl = r & 1;
  int d = dl*2 + (h >> 2), b = h & 3;
  qsfF[(((size_t)(u*NN + i)) << 7) + ss*32 + lo*16 + d*4 + b] =
      (unsigned char)__float2int_rn(p * 127.f);
}

// Kernel 2: Mmat[h,k] upper-tri 36 entries via atomics.
__global__ void k_mmat(const float* __restrict__ sf, float* __restrict__ Mmat) {
  int i = blockIdx.x, j = threadIdx.x;
  float v[HH];
#pragma unroll
  for (int h = 0; h < HH; ++h) v[h] = sf[(h*NN + i)*NN + j];
  float pr[36];
  {
    int idx = 0;
#pragma unroll
    for (int h = 0; h < HH; ++h)
#pragma unroll
      for (int k = h; k < HH; ++k) pr[idx++] = v[h]*v[k];
  }
#pragma unroll
  for (int x = 0; x < 36; ++x) {
#pragma unroll
    for (int o = 32; o; o >>= 1) pr[x] += __shfl_xor(pr[x], o);
  }
  __shared__ float mm[4][36];
  int w = j >> 6;
  if ((j & 63) == 0) {
#pragma unroll
    for (int x = 0; x < 36; ++x) mm[w][x] = pr[x];
  }
  __syncthreads();
  if (j < 36) atomicAdd(&Mmat[j], mm[0][j] + mm[1][j] + mm[2][j] + mm[3][j]);
}

// Kernel 3: big GEMM in int8, barrier-free, ONE WAVE PER BLOCK (TLP over ILP:
// ~21 independent waves/CU hide the L2/DS chains). Wave = 64 rows x 64 cols,
// MFMA i32_32x32x32_i8. One ds_bpermute gathers 4 heads (bytes of qVt dword);
// gathered dwords ARE the B-operand dwords (k-order pi chosen to match).
// Unit = 16 j x 8 h = 128 k; half-unit dbuf phases (no spill, VGPR ~64).
__global__ __launch_bounds__(64, 6) void k_gemm(
    const unsigned char* __restrict__ qsfF, const unsigned char* __restrict__ qVt,
    const float* __restrict__ sVbuf,
    const int* __restrict__ Z1, const unsigned char* __restrict__ Z2t,
    float* __restrict__ Sexp, float* __restrict__ Ene) {
  const int l  = threadIdx.x;     // 0..63
  const int lc = l & 31;          // col (B/C) / row (A) lane index
  const int lo = l >> 5;          // k-octet selector

  // XCD swizzle: grid 5376 = 8 xcd x (8 mblk x 21 a x 4 rowgroup); rowgroup
  // fastest, then a -> per-XCD L2 set ~1.2 MB (qsfF + Z2t/Z1 slices).
  const int bid  = blockIdx.x;
  const int xcd  = bid & 7;
  const int q    = bid >> 3;        // 0..671
  const int mo8  = q / 84;          // 0..7   (84 = 21*4)
  const int rem  = q - mo8*84;
  const int a_blk = rem >> 2;       // 0..20
  const int w     = rem & 3;        // 0..3 row-group
  const int mblk  = xcd*8 + mo8;    // 0..63
  const int m0 = mblk * 64;
  const int wrow = w * 64;

  i32x16 acc[2][2];               // [mr][ct]
#pragma unroll
  for (int mr = 0; mr < 2; ++mr)
#pragma unroll
    for (int ct = 0; ct < 2; ++ct)
#pragma unroll
      for (int r = 0; r < 16; ++r) acc[mr][ct][r] = 0;

  // gather tables: lane c<21 holds qV dwords for (a_blk, c): heads 0-3, 4-7
  const int lc21 = (lc < Q1c) ? lc : (Q1c - 1);
  const int tab0 = *reinterpret_cast<const int*>(qVt + (a_blk*Q2c + lc21)*8);
  const int tab1 = *reinterpret_cast<const int*>(qVt + (a_blk*Q2c + lc21)*8 + 4);

  const unsigned char* zrow = Z2t + ((size_t)(m0 + lc)) * 8;

  uint2 za[2], zb[2];             // [ct]
  int   ga[2][4][2], gb[2][4][2]; // [ct][r][hq]
  i32x4 Aa[2][2], Ab[2][2];       // [s01][mr]

#define ZLOADU(uu, zd)                                                         \
  {                                                                            \
    const int uc = ((uu) > 15) ? 15 : (uu);                                    \
    const int jb = uc*2 + lo;                                                  \
    zd[0] = *reinterpret_cast<const uint2*>(zrow + ((size_t)jb*MM)*8);         \
    zd[1] = *reinterpret_cast<const uint2*>(zrow + ((size_t)jb*MM + 32)*8);    \
  }

#define GATH(gd, zs, HF)                                                       \
  {                                                                            \
    _Pragma("unroll")                                                          \
    for (int ct = 0; ct < 2; ++ct) {                                           \
      const unsigned zz = (HF) ? zs[ct].y : zs[ct].x;                          \
      _Pragma("unroll")                                                        \
      for (int r = 0; r < 4; ++r) {                                            \
        const int c = (int)((zz >> (8*r)) & 255u) << 2;                        \
        gd[ct][r][0] = __builtin_amdgcn_ds_bpermute(c, tab0);                  \
        gd[ct][r][1] = __builtin_amdgcn_ds_bpermute(c, tab1);                  \
      }                                                                        \
    }                                                                          \
  }

#define ALOADU(uu, hf, Ad)                                                     \
  {                                                                            \
    const int uc = ((uu) > 15) ? 15 : (uu);                                    \
    const unsigned char* ab = qsfF + ((size_t)uc << 15)                        \
        + (size_t)(wrow + lc)*128 + (hf)*64 + lo*16;                           \
    _Pragma("unroll")                                                          \
    for (int s01 = 0; s01 < 2; ++s01)                                          \
      _Pragma("unroll")                                                        \
      for (int mr = 0; mr < 2; ++mr)                                           \
        Ad[s01][mr] = *reinterpret_cast<const i32x4*>(ab + s01*32 + mr*32*128);\
  }

#define MFMA8(Ad, gd)                                                          \
  {                                                                            \
    _Pragma("unroll")                                                          \
    for (int s01 = 0; s01 < 2; ++s01)                                          \
      _Pragma("unroll")                                                        \
      for (int ct = 0; ct < 2; ++ct) {                                         \
        i32x4 B = (i32x4){gd[ct][2*s01][0], gd[ct][2*s01][1],                  \
                          gd[ct][2*s01+1][0], gd[ct][2*s01+1][1]};             \
        _Pragma("unroll")                                                      \
        for (int mr = 0; mr < 2; ++mr)                                         \
          acc[mr][ct] = __builtin_amdgcn_mfma_i32_32x32x32_i8(                 \
              Ad[s01][mr], B, acc[mr][ct], 0, 0, 0);                           \
      }                                                                        \
  }

  // ---- prologue ----
  ZLOADU(0, za); ZLOADU(1, zb);
  GATH(ga, za, 0);
  ALOADU(0, 0, Aa);

  for (int u = 0; u < 16; u += 2) {
    GATH(gb, za, 1);  ALOADU(u,   1, Ab);  MFMA8(Aa, ga);
    ZLOADU(u+2, za);
    GATH(ga, zb, 0);  ALOADU(u+1, 0, Aa);  MFMA8(Ab, gb);
    GATH(gb, zb, 1);  ALOADU(u+1, 1, Ab);  MFMA8(Aa, ga);
    ZLOADU(u+3, zb);
    GATH(ga, za, 0);  ALOADU(u+2, 0, Aa);  MFMA8(Ab, gb);
  }
#undef ZLOADU
#undef GATH
#undef ALOADU
#undef MFMA8

  // ---- fused epilogue: dequant, exp-sum, Z1-selected sum per column m ----
  const float scale = sVbuf[0] * (1.f / 127.f);
#pragma unroll
  for (int ct = 0; ct < 2; ++ct) {
    const int m = m0 + ct*32 + lc;
    float se = 0.f, en = 0.f;
#pragma unroll
    for (int mr = 0; mr < 2; ++mr) {
#pragma unroll
      for (int r = 0; r < 16; ++r) {
        int row = wrow + mr*32 + (r & 3) + 8*(r >> 2) + 4*lo;
        float g = (float)acc[mr][ct][r] * scale;
        se += __expf(g);
        en += (Z1[row*MM + m] == a_blk) ? g : 0.f;
      }
    }
    se += __shfl_xor(se, 32);
    en += __shfl_xor(en, 32);
    if (lo == 0) {
      atomicAdd(&Sexp[m], se);
      atomicAdd(&Ene[m], en);
    }
  }
}

// Kernel 4: pl = -sum_m w[m]*(Ene[m] - log(Sexp[m] + 235)); block 16 adds reg term.
__global__ void k_final(const float* __restrict__ Sexp, const float* __restrict__ Ene,
                        const float* __restrict__ wts, const float* __restrict__ Mmat,
                        const float* __restrict__ Vf, float* __restrict__ out) {
  __shared__ float r4[4];
  float val = 0.f;
  if (blockIdx.x < 16) {
    int m = blockIdx.x * 256 + threadIdx.x;
    val = -wts[m] * (Ene[m] - logf(Sexp[m] + 235.0f));
  } else {
    int t = threadIdx.x;
    if (t < 64) {
      int h = t >> 3, k = t & 7;
      float dot = 0.f;
      for (int x = 0; x < Q1c*Q2c; ++x) dot += Vf[h*(Q1c*Q2c)+x] * Vf[k*(Q1c*Q2c)+x];
      int hh = (h < k) ? h : k;
      int kk = (h < k) ? k : h;
      int idx = hh*8 - (hh*(hh-1))/2 + (kk - hh);   // upper-tri index
      val = 0.001f * Mmat[idx] * dot;               // LAMBD = 0.001
    }
  }
#pragma unroll
  for (int o = 32; o; o >>= 1) val += __shfl_xor(val, o);
  int w = threadIdx.x >> 6;
  if ((threadIdx.x & 63) == 0) r4[w] = val;
  __syncthreads();
  if (threadIdx.x == 0) atomicAdd(out, r4[0] + r4[1] + r4[2] + r4[3]);
}

extern "C" void kernel_launch(void* const* d_in, const int* in_sizes, int n_in,
                              void* d_out, int out_size, void* d_ws, size_t ws_size,
                              hipStream_t stream) {
  const float* Q   = (const float*)d_in[0];
  const float* K   = (const float*)d_in[1];
  const float* V   = (const float*)d_in[2];
  const int*   Z1  = (const int*)d_in[3];
  const int*   Z2  = (const int*)d_in[4];
  const float* wts = (const float*)d_in[5];
  float* out = (float*)d_out;

  char* ws = (char*)d_ws;
  float*          sf   = (float*)ws;                               // 2 MB
  unsigned char*  qsfF = (unsigned char*)(ws + (2u << 20));        // 512 KB
  unsigned char*  Z2t  = (unsigned char*)(ws + (3u << 20));        // 1 MB
  float*          Sexp = (float*)(ws + (4u << 20));                // 16 KB
  float*          Ene  = (float*)(ws + (4u << 20) + (16u << 10));  // 16 KB
  float*          Mmat = (float*)(ws + (4u << 20) + (32u << 10));  // 144 B
  unsigned char*  qVt  = (unsigned char*)(ws + (4u << 20) + (40u << 10)); // 3528 B
  float*          sVbuf= (float*)(ws + (4u << 20) + (48u << 10));  // 4 B

  hipMemsetAsync(out, 0, sizeof(float), stream);
  hipMemsetAsync(ws + (4u << 20), 0, (33u << 10), stream);

  k_pack   <<<dim3(512),  dim3(256), 0, stream>>>(Z2, Z2t);
  k_prep   <<<dim3(1),    dim3(256), 0, stream>>>(V, qVt, sVbuf);
  k_softmax<<<dim3(2048), dim3(256), 0, stream>>>(Q, K, sf, qsfF);
  k_mmat   <<<dim3(256),  dim3(256), 0, stream>>>(sf, Mmat);
  k_gemm   <<<dim3(5376), dim3(64),  0, stream>>>(qsfF, qVt, sVbuf, Z1, Z2t, Sexp, Ene);
  k_final  <<<dim3(17),   dim3(256), 0, stream>>>(Sexp, Ene, wts, Mmat, V, out);
}

// Round 9
// 142.131 us; speedup vs baseline: 6.4334x; 6.4334x over previous
//
#include <hip/hip_runtime.h>
#include <hip/hip_bf16.h>

#define HH 8
#define DD 64
#define NN 256
#define Q1c 21
#define Q2c 21
#define MM 4096
#define KTOT 2048   // HH*NN

typedef __attribute__((ext_vector_type(4))) int i32x4;
typedef __attribute__((ext_vector_type(16))) int i32x16;

// Kernel 0: pack Z2 (int32 [j][m]) -> Z2t bytes [j/8][m][8] so k_gemm loads
// 8 indices with one dwordx2.
__global__ void k_pack(const int* __restrict__ Z2, unsigned char* __restrict__ Z2t) {
  int jb = blockIdx.x >> 4;                       // 0..31
  int m  = ((blockIdx.x & 15) << 8) + threadIdx.x;
  unsigned lo = 0, hi = 0;
#pragma unroll
  for (int r = 0; r < 4; ++r) lo |= ((unsigned)Z2[(jb*8 + r)*MM + m] & 255u) << (8*r);
#pragma unroll
  for (int r = 0; r < 4; ++r) hi |= ((unsigned)Z2[(jb*8 + 4 + r)*MM + m] & 255u) << (8*r);
  uint2 v; v.x = lo; v.y = hi;
  *reinterpret_cast<uint2*>(Z2t + ((size_t)jb*MM + m)*8) = v;
}

// Kernel 0b: quantize V: sV = max|V|/127; qVt[(a*21+c)*8 + h] = round(V[h][a][c]/sV).
__global__ void k_prep(const float* __restrict__ Vf, unsigned char* __restrict__ qVt,
                       float* __restrict__ sVbuf) {
  __shared__ float red[4];
  int t = threadIdx.x;
  float mx = 0.f;
  for (int x = t; x < HH*Q1c*Q2c; x += 256) mx = fmaxf(mx, fabsf(Vf[x]));
#pragma unroll
  for (int o = 32; o; o >>= 1) mx = fmaxf(mx, __shfl_xor(mx, o));
  if ((t & 63) == 0) red[t >> 6] = mx;
  __syncthreads();
  mx = fmaxf(fmaxf(red[0], red[1]), fmaxf(red[2], red[3]));
  if (t == 0) sVbuf[0] = mx / 127.f;
  float inv = 127.f / mx;
  for (int x = t; x < HH*Q1c*Q2c; x += 256) {
    int h = x / (Q1c*Q2c);
    int rem = x - h*(Q1c*Q2c);
    int a = rem / Q2c, c = rem - a*Q2c;
    int qv = __float2int_rn(Vf[x] * inv);
    qVt[(a*Q2c + c)*8 + h] = (unsigned char)(qv & 255);
  }
}

// Kernel 1: e = Q^T K per head, softmax over j. Writes sf (f32, for k_mmat) and
// qsfF: u8 A-operand pre-fragmented for i8 MFMA with k-order pi(s,lo,d,b):
// j = u*16 + 8*lo + 2*s01(+hf*4) + (d>>1), h = (d&1)*4 + b.
__global__ void k_softmax(const float* __restrict__ Q, const float* __restrict__ K,
                          float* __restrict__ sf, unsigned char* __restrict__ qsfF) {
  int h = blockIdx.x >> 8;
  int i = blockIdx.x & 255;
  int j = threadIdx.x;
  __shared__ float qs[DD];
  __shared__ float red[4];
  if (j < DD) qs[j] = Q[(h*DD + j)*NN + i];
  __syncthreads();
  float e = 0.f;
#pragma unroll
  for (int d = 0; d < DD; ++d) e = fmaf(qs[d], K[(h*DD + d)*NN + j], e);
  float mx = e;
#pragma unroll
  for (int o = 32; o; o >>= 1) mx = fmaxf(mx, __shfl_xor(mx, o));
  if ((j & 63) == 0) red[j >> 6] = mx;
  __syncthreads();
  mx = fmaxf(fmaxf(red[0], red[1]), fmaxf(red[2], red[3]));
  float p = __expf(e - mx);
  float s = p;
#pragma unroll
  for (int o = 32; o; o >>= 1) s += __shfl_xor(s, o);
  __syncthreads();
  if ((j & 63) == 0) red[j >> 6] = s;
  __syncthreads();
  s = red[0] + red[1] + red[2] + red[3];
  p = p / s;
  sf[(h*NN + i)*NN + j] = p;
  // i8 fragment placement
  int u = j >> 4, r8 = j & 15;
  int lo = r8 >> 3, r = r8 & 7;
  int ss = r >> 1, dl = r & 1;
  int d = dl*2 + (h >> 2), b = h & 3;
  qsfF[(((size_t)(u*NN + i)) << 7) + ss*32 + lo*16 + d*4 + b] =
      (unsigned char)__float2int_rn(p * 127.f);
}

// Kernel 2: Mmat[h,k] upper-tri 36 entries via atomics.
__global__ void k_mmat(const float* __restrict__ sf, float* __restrict__ Mmat) {
  int i = blockIdx.x, j = threadIdx.x;
  float v[HH];
#pragma unroll
  for (int h = 0; h < HH; ++h) v[h] = sf[(h*NN + i)*NN + j];
  float pr[36];
  {
    int idx = 0;
#pragma unroll
    for (int h = 0; h < HH; ++h)
#pragma unroll
      for (int k = h; k < HH; ++k) pr[idx++] = v[h]*v[k];
  }
#pragma unroll
  for (int x = 0; x < 36; ++x) {
#pragma unroll
    for (int o = 32; o; o >>= 1) pr[x] += __shfl_xor(pr[x], o);
  }
  __shared__ float mm[4][36];
  int w = j >> 6;
  if ((j & 63) == 0) {
#pragma unroll
    for (int x = 0; x < 36; ++x) mm[w][x] = pr[x];
  }
  __syncthreads();
  if (j < 36) atomicAdd(&Mmat[j], mm[0][j] + mm[1][j] + mm[2][j] + mm[3][j]);
}

// Kernel 3: big GEMM in int8, ONE WAVE PER BLOCK (16 independent waves/CU),
// MFMA i32_32x32x32_i8, wave = 64 rows x 64 cols. B gathered per Z2 index with
// ONE ds_read_b64 from a 32x-replicated LDS table of the 21 (4-head dword
// pair) qV entries — single-wave block => table needs no barriers in use.
// launch_bounds(64,4): VGPR cap 128 = 64 arch + 64 acc, NO SPILL (R8 lesson).
__global__ __launch_bounds__(64, 4) void k_gemm(
    const unsigned char* __restrict__ qsfF, const unsigned char* __restrict__ qVt,
    const float* __restrict__ sVbuf,
    const int* __restrict__ Z1, const unsigned char* __restrict__ Z2t,
    float* __restrict__ Sexp, float* __restrict__ Ene) {
  __shared__ int tbl[32 * 42];    // [rep][c]: int2 at dword (rep*42 + 2c); 5376 B

  const int l  = threadIdx.x;     // 0..63
  const int lc = l & 31;          // col (B/C) / row (A) lane index
  const int lo = l >> 5;          // k-octet selector

  // XCD swizzle: grid 5376 = 8 xcd x (8 mblk x 21 a x 4 rowgroup); rowgroup
  // fastest, then a -> per-XCD L2 set ~1.2 MB (qsfF + Z2t/Z1 slices).
  const int bid  = blockIdx.x;
  const int xcd  = bid & 7;
  const int q    = bid >> 3;        // 0..671
  const int mo8  = q / 84;          // 0..7   (84 = 21*4)
  const int rem  = q - mo8*84;
  const int a_blk = rem >> 2;       // 0..20
  const int w     = rem & 3;        // 0..3 row-group
  const int mblk  = xcd*8 + mo8;    // 0..63
  const int m0 = mblk * 64;
  const int wrow = w * 64;

  // ---- build replicated gather table (single wave: no barrier needed after
  // __syncthreads; lane c<21 writes all 32 replicas of its entry) ----
  if (l < Q1c) {
    int2 v = *reinterpret_cast<const int2*>(qVt + (a_blk*Q2c + l)*8);
#pragma unroll
    for (int rep = 0; rep < 32; ++rep)
      *reinterpret_cast<int2*>(&tbl[rep*42 + 2*l]) = v;
  }
  __syncthreads();
  const int tbase = (l & 31) * 42;  // this lane's replica (dword offset)

  i32x16 acc[2][2];               // [mr][ct]
#pragma unroll
  for (int mr = 0; mr < 2; ++mr)
#pragma unroll
    for (int ct = 0; ct < 2; ++ct)
#pragma unroll
      for (int r = 0; r < 16; ++r) acc[mr][ct][r] = 0;

  const unsigned char* zrow = Z2t + ((size_t)(m0 + lc)) * 8;

  uint2 za[2], zb[2];             // [ct]
  int   ga[2][4][2], gb[2][4][2]; // [ct][r][hq]
  i32x4 Aa[2][2], Ab[2][2];       // [s01][mr]

#define ZLOADU(uu, zd)                                                         \
  {                                                                            \
    const int uc = ((uu) > 15) ? 15 : (uu);                                    \
    const int jb = uc*2 + lo;                                                  \
    zd[0] = *reinterpret_cast<const uint2*>(zrow + ((size_t)jb*MM)*8);         \
    zd[1] = *reinterpret_cast<const uint2*>(zrow + ((size_t)jb*MM + 32)*8);    \
  }

#define GATH(gd, zs, HF)                                                       \
  {                                                                            \
    _Pragma("unroll")                                                          \
    for (int ct = 0; ct < 2; ++ct) {                                           \
      const unsigned zz = (HF) ? zs[ct].y : zs[ct].x;                          \
      _Pragma("unroll")                                                        \
      for (int r = 0; r < 4; ++r) {                                            \
        const int c = (int)((zz >> (8*r)) & 255u);                             \
        int2 gg = *reinterpret_cast<const int2*>(&tbl[tbase + (c << 1)]);      \
        gd[ct][r][0] = gg.x;                                                   \
        gd[ct][r][1] = gg.y;                                                   \
      }                                                                        \
    }                                                                          \
  }

#define ALOADU(uu, hf, Ad)                                                     \
  {                                                                            \
    const int uc = ((uu) > 15) ? 15 : (uu);                                    \
    const unsigned char* ab = qsfF + ((size_t)uc << 15)                        \
        + (size_t)(wrow + lc)*128 + (hf)*64 + lo*16;                           \
    _Pragma("unroll")                                                          \
    for (int s01 = 0; s01 < 2; ++s01)                                          \
      _Pragma("unroll")                                                        \
      for (int mr = 0; mr < 2; ++mr)                                           \
        Ad[s01][mr] = *reinterpret_cast<const i32x4*>(ab + s01*32 + mr*32*128);\
  }

#define MFMA8(Ad, gd)                                                          \
  {                                                                            \
    _Pragma("unroll")                                                          \
    for (int s01 = 0; s01 < 2; ++s01)                                          \
      _Pragma("unroll")                                                        \
      for (int ct = 0; ct < 2; ++ct) {                                         \
        i32x4 B = (i32x4){gd[ct][2*s01][0], gd[ct][2*s01][1],                  \
                          gd[ct][2*s01+1][0], gd[ct][2*s01+1][1]};             \
        _Pragma("unroll")                                                      \
        for (int mr = 0; mr < 2; ++mr)                                         \
          acc[mr][ct] = __builtin_amdgcn_mfma_i32_32x32x32_i8(                 \
              Ad[s01][mr], B, acc[mr][ct], 0, 0, 0);                           \
      }                                                                        \
  }

  // ---- prologue ----
  ZLOADU(0, za); ZLOADU(1, zb);
  GATH(ga, za, 0);
  ALOADU(0, 0, Aa);

  for (int u = 0; u < 16; u += 2) {
    GATH(gb, za, 1);  ALOADU(u,   1, Ab);  MFMA8(Aa, ga);
    ZLOADU(u+2, za);
    GATH(ga, zb, 0);  ALOADU(u+1, 0, Aa);  MFMA8(Ab, gb);
    GATH(gb, zb, 1);  ALOADU(u+1, 1, Ab);  MFMA8(Aa, ga);
    ZLOADU(u+3, zb);
    GATH(ga, za, 0);  ALOADU(u+2, 0, Aa);  MFMA8(Ab, gb);
  }
#undef ZLOADU
#undef GATH
#undef ALOADU
#undef MFMA8

  // ---- fused epilogue: dequant, exp-sum, Z1-selected sum per column m ----
  const float scale = sVbuf[0] * (1.f / 127.f);
#pragma unroll
  for (int ct = 0; ct < 2; ++ct) {
    const int m = m0 + ct*32 + lc;
    float se = 0.f, en = 0.f;
#pragma unroll
    for (int mr = 0; mr < 2; ++mr) {
#pragma unroll
      for (int r = 0; r < 16; ++r) {
        int row = wrow + mr*32 + (r & 3) + 8*(r >> 2) + 4*lo;
        float g = (float)acc[mr][ct][r] * scale;
        se += __expf(g);
        en += (Z1[row*MM + m] == a_blk) ? g : 0.f;
      }
    }
    se += __shfl_xor(se, 32);
    en += __shfl_xor(en, 32);
    if (lo == 0) {
      atomicAdd(&Sexp[m], se);
      atomicAdd(&Ene[m], en);
    }
  }
}

// Kernel 4: pl = -sum_m w[m]*(Ene[m] - log(Sexp[m] + 235)); block 16 adds reg term.
__global__ void k_final(const float* __restrict__ Sexp, const float* __restrict__ Ene,
                        const float* __restrict__ wts, const float* __restrict__ Mmat,
                        const float* __restrict__ Vf, float* __restrict__ out) {
  __shared__ float r4[4];
  float val = 0.f;
  if (blockIdx.x < 16) {
    int m = blockIdx.x * 256 + threadIdx.x;
    val = -wts[m] * (Ene[m] - logf(Sexp[m] + 235.0f));
  } else {
    int t = threadIdx.x;
    if (t < 64) {
      int h = t >> 3, k = t & 7;
      float dot = 0.f;
      for (int x = 0; x < Q1c*Q2c; ++x) dot += Vf[h*(Q1c*Q2c)+x] * Vf[k*(Q1c*Q2c)+x];
      int hh = (h < k) ? h : k;
      int kk = (h < k) ? k : h;
      int idx = hh*8 - (hh*(hh-1))/2 + (kk - hh);   // upper-tri index
      val = 0.001f * Mmat[idx] * dot;               // LAMBD = 0.001
    }
  }
#pragma unroll
  for (int o = 32; o; o >>= 1) val += __shfl_xor(val, o);
  int w = threadIdx.x >> 6;
  if ((threadIdx.x & 63) == 0) r4[w] = val;
  __syncthreads();
  if (threadIdx.x == 0) atomicAdd(out, r4[0] + r4[1] + r4[2] + r4[3]);
}

extern "C" void kernel_launch(void* const* d_in, const int* in_sizes, int n_in,
                              void* d_out, int out_size, void* d_ws, size_t ws_size,
                              hipStream_t stream) {
  const float* Q   = (const float*)d_in[0];
  const float* K   = (const float*)d_in[1];
  const float* V   = (const float*)d_in[2];
  const int*   Z1  = (const int*)d_in[3];
  const int*   Z2  = (const int*)d_in[4];
  const float* wts = (const float*)d_in[5];
  float* out = (float*)d_out;

  char* ws = (char*)d_ws;
  float*          sf   = (float*)ws;                               // 2 MB
  unsigned char*  qsfF = (unsigned char*)(ws + (2u << 20));        // 512 KB
  unsigned char*  Z2t  = (unsigned char*)(ws + (3u << 20));        // 1 MB
  float*          Sexp = (float*)(ws + (4u << 20));                // 16 KB
  float*          Ene  = (float*)(ws + (4u << 20) + (16u << 10));  // 16 KB
  float*          Mmat = (float*)(ws + (4u << 20) + (32u << 10));  // 144 B
  unsigned char*  qVt  = (unsigned char*)(ws + (4u << 20) + (40u << 10)); // 3528 B
  float*          sVbuf= (float*)(ws + (4u << 20) + (48u << 10));  // 4 B

  hipMemsetAsync(out, 0, sizeof(float), stream);
  hipMemsetAsync(ws + (4u << 20), 0, (33u << 10), stream);

  k_pack   <<<dim3(512),  dim3(256), 0, stream>>>(Z2, Z2t);
  k_prep   <<<dim3(1),    dim3(256), 0, stream>>>(V, qVt, sVbuf);
  k_softmax<<<dim3(2048), dim3(256), 0, stream>>>(Q, K, sf, qsfF);
  k_mmat   <<<dim3(256),  dim3(256), 0, stream>>>(sf, Mmat);
  k_gemm   <<<dim3(5376), dim3(64),  0, stream>>>(qsfF, qVt, sVbuf, Z1, Z2t, Sexp, Ene);
  k_final  <<<dim3(17),   dim3(256), 0, stream>>>(Sexp, Ene, wts, Mmat, V, out);
}

// Round 10
// 95.519 us; speedup vs baseline: 9.5728x; 1.4880x over previous
//
#include <hip/hip_runtime.h>
#include <hip/hip_bf16.h>

#define HH 8
#define DD 64
#define NN 256
#define Q1c 21
#define Q2c 21
#define MM 4096
#define KTOT 2048   // HH*NN

typedef __attribute__((ext_vector_type(4))) int i32x4;
typedef __attribute__((ext_vector_type(16))) int i32x16;

__device__ inline void gload16(const void* g, void* l) {
  __builtin_amdgcn_global_load_lds(
      (const __attribute__((address_space(1))) unsigned int*)g,
      (__attribute__((address_space(3))) unsigned int*)l, 16, 0, 0);
}

// Kernel A (fused): blocks 0..511 = Z2 byte-pack; block 512 = V quantize;
// blocks 513..2560 = softmax + qsfF fragment write.
// qsfF layout (for LDS staging): byte = ((u*2+hf)*4 + (s01*2+lo))*4096 + i*16 + d*4 + b
// where j = u*16 + lo*8 + hf*4 + s01*2 + dl, d = dl*2 + (h>>2), b = h&3.
__global__ void k_combo(const int* __restrict__ Z2, unsigned char* __restrict__ Z2t,
                        const float* __restrict__ Vf, unsigned char* __restrict__ qVt,
                        float* __restrict__ sVbuf,
                        const float* __restrict__ Q, const float* __restrict__ K,
                        float* __restrict__ sf, unsigned char* __restrict__ qsfF) {
  __shared__ float qs[DD];
  __shared__ float red[4];
  const int bid = blockIdx.x;
  const int t = threadIdx.x;

  if (bid < 512) {            // ---- pack Z2 -> bytes [j/8][m][8] ----
    int jb = bid >> 4;
    int m  = ((bid & 15) << 8) + t;
    unsigned lo = 0, hi = 0;
#pragma unroll
    for (int r = 0; r < 4; ++r) lo |= ((unsigned)Z2[(jb*8 + r)*MM + m] & 255u) << (8*r);
#pragma unroll
    for (int r = 0; r < 4; ++r) hi |= ((unsigned)Z2[(jb*8 + 4 + r)*MM + m] & 255u) << (8*r);
    uint2 v; v.x = lo; v.y = hi;
    *reinterpret_cast<uint2*>(Z2t + ((size_t)jb*MM + m)*8) = v;
    return;
  }
  if (bid == 512) {           // ---- quantize V ----
    float mx = 0.f;
    for (int x = t; x < HH*Q1c*Q2c; x += 256) mx = fmaxf(mx, fabsf(Vf[x]));
#pragma unroll
    for (int o = 32; o; o >>= 1) mx = fmaxf(mx, __shfl_xor(mx, o));
    if ((t & 63) == 0) red[t >> 6] = mx;
    __syncthreads();
    mx = fmaxf(fmaxf(red[0], red[1]), fmaxf(red[2], red[3]));
    if (t == 0) sVbuf[0] = mx / 127.f;
    float inv = 127.f / mx;
    for (int x = t; x < HH*Q1c*Q2c; x += 256) {
      int h = x / (Q1c*Q2c);
      int rem = x - h*(Q1c*Q2c);
      int a = rem / Q2c, c = rem - a*Q2c;
      int qv = __float2int_rn(Vf[x] * inv);
      qVt[(a*Q2c + c)*8 + h] = (unsigned char)(qv & 255);
    }
    return;
  }
  // ---- softmax ----
  const int bb = bid - 513;
  const int h = bb >> 8;
  const int i = bb & 255;
  const int j = t;
  if (j < DD) qs[j] = Q[(h*DD + j)*NN + i];
  __syncthreads();
  float e = 0.f;
#pragma unroll
  for (int d = 0; d < DD; ++d) e = fmaf(qs[d], K[(h*DD + d)*NN + j], e);
  float mx = e;
#pragma unroll
  for (int o = 32; o; o >>= 1) mx = fmaxf(mx, __shfl_xor(mx, o));
  if ((j & 63) == 0) red[j >> 6] = mx;
  __syncthreads();
  mx = fmaxf(fmaxf(red[0], red[1]), fmaxf(red[2], red[3]));
  float p = __expf(e - mx);
  float s = p;
#pragma unroll
  for (int o = 32; o; o >>= 1) s += __shfl_xor(s, o);
  __syncthreads();
  if ((j & 63) == 0) red[j >> 6] = s;
  __syncthreads();
  s = red[0] + red[1] + red[2] + red[3];
  p = p / s;
  sf[(h*NN + i)*NN + j] = p;
  int u = j >> 4, lo2 = (j >> 3) & 1, hf = (j >> 2) & 1, s01 = (j >> 1) & 1, dl = j & 1;
  int d = dl*2 + (h >> 2), b = h & 3;
  qsfF[(size_t)((u*2 + hf)*4 + (s01*2 + lo2))*4096 + i*16 + d*4 + b] =
      (unsigned char)__float2int_rn(p * 127.f);
}

// Kernel 2: Mmat[h,k] upper-tri 36 entries via atomics.
__global__ void k_mmat(const float* __restrict__ sf, float* __restrict__ Mmat) {
  int i = blockIdx.x, j = threadIdx.x;
  float v[HH];
#pragma unroll
  for (int h = 0; h < HH; ++h) v[h] = sf[(h*NN + i)*NN + j];
  float pr[36];
  {
    int idx = 0;
#pragma unroll
    for (int h = 0; h < HH; ++h)
#pragma unroll
      for (int k = h; k < HH; ++k) pr[idx++] = v[h]*v[k];
  }
#pragma unroll
  for (int x = 0; x < 36; ++x) {
#pragma unroll
    for (int o = 32; o; o >>= 1) pr[x] += __shfl_xor(pr[x], o);
  }
  __shared__ float mm[4][36];
  int w = j >> 6;
  if ((j & 63) == 0) {
#pragma unroll
    for (int x = 0; x < 36; ++x) mm[w][x] = pr[x];
  }
  __syncthreads();
  if (j < 36) atomicAdd(&Mmat[j], mm[0][j] + mm[1][j] + mm[2][j] + mm[3][j]);
}

// Kernel 3: int8 GEMM, T3-minimal pipeline. Block = 4 waves, 256 rows x 64
// cols. A staged via global_load_lds (double-buffered 16KB half-unit tiles,
// zero VGPR cost in flight); B gathered per lane from 32x-replicated LDS
// table (ds_read_b64); 8 MFMA i32_32x32x32_i8 per step; one barrier/step.
// 4 blocks/CU co-resident cover each other's barrier drains.
__global__ __launch_bounds__(256, 4) void k_gemm(
    const unsigned char* __restrict__ qsfF, const unsigned char* __restrict__ qVt,
    const float* __restrict__ sVbuf,
    const int* __restrict__ Z1, const unsigned char* __restrict__ Z2t,
    float* __restrict__ Sexp, float* __restrict__ Ene) {
  __shared__ __align__(16) unsigned char Albs[2][16384];
  __shared__ int tbl[32 * 42];   // [rep][c] int2 at dword rep*42+2c (8B aligned)

  const int t  = threadIdx.x;
  const int w  = t >> 6;
  const int l  = t & 63;
  const int lc = l & 31;
  const int lo = l >> 5;

  // XCD swizzle: xcd = bid%8 owns mblks [xcd*8, xcd*8+8) for all 21 a's.
  const int bid  = blockIdx.x;
  const int xcd  = bid & 7;
  const int q    = bid >> 3;        // 0..167
  const int mblk = xcd*8 + q/21;    // 0..63
  const int a_blk = q - (q/21)*21;  // 0..20
  const int m0 = mblk * 64;
  const int wrow = w * 64;

  if (t < Q1c) {
    int2 v = *reinterpret_cast<const int2*>(qVt + (a_blk*Q2c + t)*8);
#pragma unroll
    for (int rep = 0; rep < 32; ++rep)
      *reinterpret_cast<int2*>(&tbl[rep*42 + 2*t]) = v;
  }

  i32x16 acc[2][2];
#pragma unroll
  for (int mr = 0; mr < 2; ++mr)
#pragma unroll
    for (int ct = 0; ct < 2; ++ct)
#pragma unroll
      for (int r = 0; r < 16; ++r) acc[mr][ct][r] = 0;

  const int tbase = lc * 42;
  const unsigned char* zrow = Z2t + ((size_t)(m0 + lc)) * 8;

  uint2 zc[2], zn[2];

#define STAGE(b, ss)                                                           \
  {                                                                            \
    const unsigned char* gs = qsfF + ((size_t)(ss) << 14) + t*16;              \
    _Pragma("unroll")                                                          \
    for (int it = 0; it < 4; ++it)                                             \
      gload16(gs + it*4096, &Albs[b][t*16 + it*4096]);                         \
  }

#define ZLD(uu, zd)                                                            \
  {                                                                            \
    const int jb = (uu)*2 + lo;                                                \
    zd[0] = *reinterpret_cast<const uint2*>(zrow + ((size_t)jb*MM)*8);         \
    zd[1] = *reinterpret_cast<const uint2*>(zrow + ((size_t)jb*MM + 32)*8);    \
  }

#define COMPUTE(cur, hf)                                                       \
  {                                                                            \
    i32x4 Ad[2][2];                                                            \
    _Pragma("unroll")                                                          \
    for (int s01 = 0; s01 < 2; ++s01)                                          \
      _Pragma("unroll")                                                        \
      for (int mr = 0; mr < 2; ++mr)                                           \
        Ad[s01][mr] = *reinterpret_cast<const i32x4*>(                         \
            &Albs[cur][(s01*2 + lo)*4096 + (wrow + mr*32 + lc)*16]);           \
    int2 g[2][2][2];                                                           \
    _Pragma("unroll")                                                          \
    for (int ct = 0; ct < 2; ++ct) {                                           \
      const unsigned zz = (hf) ? zc[ct].y : zc[ct].x;                          \
      _Pragma("unroll")                                                        \
      for (int s01 = 0; s01 < 2; ++s01)                                        \
        _Pragma("unroll")                                                      \
        for (int dl = 0; dl < 2; ++dl) {                                       \
          const int c = (int)((zz >> (8*(s01*2 + dl))) & 255u);                \
          g[ct][s01][dl] = *reinterpret_cast<const int2*>(&tbl[tbase + 2*c]);  \
        }                                                                      \
    }                                                                          \
    _Pragma("unroll")                                                          \
    for (int s01 = 0; s01 < 2; ++s01)                                          \
      _Pragma("unroll")                                                        \
      for (int ct = 0; ct < 2; ++ct) {                                         \
        i32x4 B = (i32x4){g[ct][s01][0].x, g[ct][s01][0].y,                    \
                          g[ct][s01][1].x, g[ct][s01][1].y};                   \
        _Pragma("unroll")                                                      \
        for (int mr = 0; mr < 2; ++mr)                                         \
          acc[mr][ct] = __builtin_amdgcn_mfma_i32_32x32x32_i8(                 \
              Ad[s01][mr], B, acc[mr][ct], 0, 0, 0);                           \
      }                                                                        \
  }

  // ---- prologue: stage tile 0, z for unit 0 ----
  STAGE(0, 0);
  ZLD(0, zc);
  __syncthreads();   // drains stage0 (vmcnt) + table writes

  for (int s = 0; s < 32; s += 2) {
    // even step: cur=0, hf=0; stage s+1 -> buf1; prefetch z for next unit
    STAGE(1, s + 1);
    {
      int un = (s >> 1) + 1; if (un > 15) un = 15;
      ZLD(un, zn);
    }
    COMPUTE(0, 0);
    __syncthreads();
    // odd step: cur=1, hf=1; stage s+2 -> buf0
    if (s + 2 < 32) STAGE(0, s + 2);
    COMPUTE(1, 1);
    zc[0] = zn[0]; zc[1] = zn[1];
    __syncthreads();
  }
#undef STAGE
#undef ZLD
#undef COMPUTE

  // ---- fused epilogue: dequant, exp-sum, Z1-selected sum per column m ----
  const float scale = sVbuf[0] * (1.f / 127.f);
#pragma unroll
  for (int ct = 0; ct < 2; ++ct) {
    const int m = m0 + ct*32 + lc;
    float se = 0.f, en = 0.f;
#pragma unroll
    for (int mr = 0; mr < 2; ++mr) {
#pragma unroll
      for (int r = 0; r < 16; ++r) {
        int row = wrow + mr*32 + (r & 3) + 8*(r >> 2) + 4*lo;
        float g = (float)acc[mr][ct][r] * scale;
        se += __expf(g);
        en += (Z1[row*MM + m] == a_blk) ? g : 0.f;
      }
    }
    se += __shfl_xor(se, 32);
    en += __shfl_xor(en, 32);
    if (lo == 0) {
      atomicAdd(&Sexp[m], se);
      atomicAdd(&Ene[m], en);
    }
  }
}

// Kernel 4: pl = -sum_m w[m]*(Ene[m] - log(Sexp[m] + 235)); block 16 adds reg term.
__global__ void k_final(const float* __restrict__ Sexp, const float* __restrict__ Ene,
                        const float* __restrict__ wts, const float* __restrict__ Mmat,
                        const float* __restrict__ Vf, float* __restrict__ out) {
  __shared__ float r4[4];
  float val = 0.f;
  if (blockIdx.x < 16) {
    int m = blockIdx.x * 256 + threadIdx.x;
    val = -wts[m] * (Ene[m] - logf(Sexp[m] + 235.0f));
  } else {
    int t = threadIdx.x;
    if (t < 64) {
      int h = t >> 3, k = t & 7;
      float dot = 0.f;
      for (int x = 0; x < Q1c*Q2c; ++x) dot += Vf[h*(Q1c*Q2c)+x] * Vf[k*(Q1c*Q2c)+x];
      int hh = (h < k) ? h : k;
      int kk = (h < k) ? k : h;
      int idx = hh*8 - (hh*(hh-1))/2 + (kk - hh);   // upper-tri index
      val = 0.001f * Mmat[idx] * dot;               // LAMBD = 0.001
    }
  }
#pragma unroll
  for (int o = 32; o; o >>= 1) val += __shfl_xor(val, o);
  int w = threadIdx.x >> 6;
  if ((threadIdx.x & 63) == 0) r4[w] = val;
  __syncthreads();
  if (threadIdx.x == 0) atomicAdd(out, r4[0] + r4[1] + r4[2] + r4[3]);
}

extern "C" void kernel_launch(void* const* d_in, const int* in_sizes, int n_in,
                              void* d_out, int out_size, void* d_ws, size_t ws_size,
                              hipStream_t stream) {
  const float* Q   = (const float*)d_in[0];
  const float* K   = (const float*)d_in[1];
  const float* V   = (const float*)d_in[2];
  const int*   Z1  = (const int*)d_in[3];
  const int*   Z2  = (const int*)d_in[4];
  const float* wts = (const float*)d_in[5];
  float* out = (float*)d_out;

  char* ws = (char*)d_ws;
  float*          sf   = (float*)ws;                               // 2 MB
  unsigned char*  qsfF = (unsigned char*)(ws + (2u << 20));        // 512 KB
  unsigned char*  Z2t  = (unsigned char*)(ws + (3u << 20));        // 1 MB
  float*          Sexp = (float*)(ws + (4u << 20));                // 16 KB
  float*          Ene  = (float*)(ws + (4u << 20) + (16u << 10));  // 16 KB
  float*          Mmat = (float*)(ws + (4u << 20) + (32u << 10));  // 144 B
  unsigned char*  qVt  = (unsigned char*)(ws + (4u << 20) + (40u << 10)); // 3528 B
  float*          sVbuf= (float*)(ws + (4u << 20) + (48u << 10));  // 4 B

  hipMemsetAsync(out, 0, sizeof(float), stream);
  hipMemsetAsync(ws + (4u << 20), 0, (33u << 10), stream);

  k_combo  <<<dim3(2561), dim3(256), 0, stream>>>(Z2, Z2t, V, qVt, sVbuf, Q, K, sf, qsfF);
  k_mmat   <<<dim3(256),  dim3(256), 0, stream>>>(sf, Mmat);
  k_gemm   <<<dim3(1344), dim3(256), 0, stream>>>(qsfF, qVt, sVbuf, Z1, Z2t, Sexp, Ene);
  k_final  <<<dim3(17),   dim3(256), 0, stream>>>(Sexp, Ene, wts, Mmat, V, out);
}

// Round 11
// 83.627 us; speedup vs baseline: 10.9341x; 1.1422x over previous
//
#include <hip/hip_runtime.h>
#include <hip/hip_bf16.h>

#define HH 8
#define DD 64
#define NN 256
#define Q1c 21
#define Q2c 21
#define MM 4096
#define KTOT 2048   // HH*NN

typedef __attribute__((ext_vector_type(4))) int i32x4;
typedef __attribute__((ext_vector_type(16))) int i32x16;

// Kernel A (fused): blocks 0..511 = Z2 byte-pack; block 512 = V quantize;
// blocks 513..2560 = softmax + qsfF fragment write.
// qsfF layout: byte = ((u*2+hf)*4 + (s01*2+lo))*4096 + i*16 + d*4 + b
// where j = u*16 + lo*8 + hf*4 + s01*2 + dl, d = dl*2 + (h>>2), b = h&3.
__global__ void k_combo(const int* __restrict__ Z2, unsigned char* __restrict__ Z2t,
                        const float* __restrict__ Vf, unsigned char* __restrict__ qVt,
                        float* __restrict__ sVbuf,
                        const float* __restrict__ Q, const float* __restrict__ K,
                        float* __restrict__ sf, unsigned char* __restrict__ qsfF) {
  __shared__ float qs[DD];
  __shared__ float red[4];
  const int bid = blockIdx.x;
  const int t = threadIdx.x;

  if (bid < 512) {            // ---- pack Z2 -> bytes [j/8][m][8] ----
    int jb = bid >> 4;
    int m  = ((bid & 15) << 8) + t;
    unsigned lo = 0, hi = 0;
#pragma unroll
    for (int r = 0; r < 4; ++r) lo |= ((unsigned)Z2[(jb*8 + r)*MM + m] & 255u) << (8*r);
#pragma unroll
    for (int r = 0; r < 4; ++r) hi |= ((unsigned)Z2[(jb*8 + 4 + r)*MM + m] & 255u) << (8*r);
    uint2 v; v.x = lo; v.y = hi;
    *reinterpret_cast<uint2*>(Z2t + ((size_t)jb*MM + m)*8) = v;
    return;
  }
  if (bid == 512) {           // ---- quantize V ----
    float mx = 0.f;
    for (int x = t; x < HH*Q1c*Q2c; x += 256) mx = fmaxf(mx, fabsf(Vf[x]));
#pragma unroll
    for (int o = 32; o; o >>= 1) mx = fmaxf(mx, __shfl_xor(mx, o));
    if ((t & 63) == 0) red[t >> 6] = mx;
    __syncthreads();
    mx = fmaxf(fmaxf(red[0], red[1]), fmaxf(red[2], red[3]));
    if (t == 0) sVbuf[0] = mx / 127.f;
    float inv = 127.f / mx;
    for (int x = t; x < HH*Q1c*Q2c; x += 256) {
      int h = x / (Q1c*Q2c);
      int rem = x - h*(Q1c*Q2c);
      int a = rem / Q2c, c = rem - a*Q2c;
      int qv = __float2int_rn(Vf[x] * inv);
      qVt[(a*Q2c + c)*8 + h] = (unsigned char)(qv & 255);
    }
    return;
  }
  // ---- softmax ----
  const int bb = bid - 513;
  const int h = bb >> 8;
  const int i = bb & 255;
  const int j = t;
  if (j < DD) qs[j] = Q[(h*DD + j)*NN + i];
  __syncthreads();
  float e = 0.f;
#pragma unroll
  for (int d = 0; d < DD; ++d) e = fmaf(qs[d], K[(h*DD + d)*NN + j], e);
  float mx = e;
#pragma unroll
  for (int o = 32; o; o >>= 1) mx = fmaxf(mx, __shfl_xor(mx, o));
  if ((j & 63) == 0) red[j >> 6] = mx;
  __syncthreads();
  mx = fmaxf(fmaxf(red[0], red[1]), fmaxf(red[2], red[3]));
  float p = __expf(e - mx);
  float s = p;
#pragma unroll
  for (int o = 32; o; o >>= 1) s += __shfl_xor(s, o);
  __syncthreads();
  if ((j & 63) == 0) red[j >> 6] = s;
  __syncthreads();
  s = red[0] + red[1] + red[2] + red[3];
  p = p / s;
  sf[(h*NN + i)*NN + j] = p;
  int u = j >> 4, lo2 = (j >> 3) & 1, hf = (j >> 2) & 1, s01 = (j >> 1) & 1, dl = j & 1;
  int d = dl*2 + (h >> 2), b = h & 3;
  qsfF[(size_t)((u*2 + hf)*4 + (s01*2 + lo2))*4096 + i*16 + d*4 + b] =
      (unsigned char)__float2int_rn(p * 127.f);
}

// Kernel 2: Mmat upper-tri 36 sums. 64 blocks; each thread accumulates 4
// (i,j) points in registers, then one wave/block reduction + atomics.
__global__ void k_mmat(const float* __restrict__ sf, float* __restrict__ Mmat) {
  const int t = threadIdx.x;
  float pr[36];
#pragma unroll
  for (int x = 0; x < 36; ++x) pr[x] = 0.f;
#pragma unroll
  for (int k = 0; k < 4; ++k) {
    int p = blockIdx.x*1024 + k*256 + t;
    int i = p >> 8, j = p & 255;
    float v[HH];
#pragma unroll
    for (int h = 0; h < HH; ++h) v[h] = sf[(h*NN + i)*NN + j];
    int idx = 0;
#pragma unroll
    for (int h = 0; h < HH; ++h)
#pragma unroll
      for (int k2 = h; k2 < HH; ++k2) pr[idx++] += v[h]*v[k2];
  }
#pragma unroll
  for (int x = 0; x < 36; ++x) {
#pragma unroll
    for (int o = 32; o; o >>= 1) pr[x] += __shfl_xor(pr[x], o);
  }
  __shared__ float mm[4][36];
  int w = t >> 6;
  if ((t & 63) == 0) {
#pragma unroll
    for (int x = 0; x < 36; ++x) mm[w][x] = pr[x];
  }
  __syncthreads();
  if (t < 36) atomicAdd(&Mmat[t], mm[0][t] + mm[1][t] + mm[2][t] + mm[3][t]);
}

// Kernel 3: int8 GEMM. 4 waves x (64 rows x 64 cols). A straight from global
// (L2-hot qsfF, coalesced dwordx4 -> VMEM pipe). B built cooperatively ONCE
// per block per step: 256 threads each build one 16B fragment chunk (2 tbl
// ds_read_b64 + 1 ds_write_b128) into double-buffered XOR-swizzled LDS; each
// wave reads fragments with 4x ds_read_b128 (conflict-free). One barrier per
// step. DS bytes/step ~4x lower than R10 (A off the LDS pipe, B dedup'd).
__global__ __launch_bounds__(256, 4) void k_gemm(
    const unsigned char* __restrict__ qsfF, const unsigned char* __restrict__ qVt,
    const float* __restrict__ sVbuf,
    const int* __restrict__ Z1, const unsigned char* __restrict__ Z2t,
    float* __restrict__ Sexp, float* __restrict__ Ene) {
  __shared__ __align__(16) unsigned char Bl[2][4096];
  __shared__ int tbl[32 * 42];   // [rep][c] int2 at dword rep*42+2c

  const int t  = threadIdx.x;
  const int w  = t >> 6;
  const int l  = t & 63;
  const int lc = l & 31;
  const int lo = l >> 5;

  // XCD swizzle: xcd = bid%8 owns mblks [xcd*8, xcd*8+8) for all 21 a's.
  const int bid  = blockIdx.x;
  const int xcd  = bid & 7;
  const int q    = bid >> 3;        // 0..167
  const int mblk = xcd*8 + q/21;    // 0..63
  const int a_blk = q - (q/21)*21;  // 0..20
  const int m0 = mblk * 64;
  const int wrow = w * 64;

  // build-role indices (block-wide cooperative B build)
  const int bcol = t & 63;          // column within tile
  const int bkg  = (t >> 6) & 1;    // k-group (lo')
  const int bs   = t >> 7;          // s01'
  const int brep = (t & 31) * 42;   // tbl replica base (dwords)
  const int boff = ((bs*2048) + bcol*32 + bkg*16) ^ ((bcol & 4) << 2);
  const unsigned char* zcolp = Z2t + (size_t)(m0 + bcol) * 8;

  // fragment-read offsets (per lane)
  const int roff = (lc*32 + lo*16) ^ ((lc & 4) << 2);
  const size_t aoff = (size_t)lo*4096 + (size_t)(wrow + lc)*16;

  if (t < Q1c) {
    int2 v = *reinterpret_cast<const int2*>(qVt + (a_blk*Q2c + t)*8);
#pragma unroll
    for (int rep = 0; rep < 32; ++rep)
      *reinterpret_cast<int2*>(&tbl[rep*42 + 2*t]) = v;
  }

  i32x16 acc[2][2];
#pragma unroll
  for (int mr = 0; mr < 2; ++mr)
#pragma unroll
    for (int ct = 0; ct < 2; ++ct)
#pragma unroll
      for (int r = 0; r < 16; ++r) acc[mr][ct][r] = 0;

#define ZLDU(uu, zd)                                                           \
  {                                                                            \
    const int uc = ((uu) > 15) ? 15 : (uu);                                    \
    zd = *reinterpret_cast<const uint2*>(zcolp + ((size_t)(uc*2 + bkg)*MM)*8); \
  }

#define ALOADG(ss, Ad)                                                         \
  {                                                                            \
    const int sc = ((ss) > 31) ? 31 : (ss);                                    \
    const unsigned char* ap = qsfF + ((size_t)sc << 14) + aoff;                \
    _Pragma("unroll")                                                          \
    for (int s01 = 0; s01 < 2; ++s01)                                          \
      _Pragma("unroll")                                                        \
      for (int mr = 0; mr < 2; ++mr)                                           \
        Ad[s01][mr] = *reinterpret_cast<const i32x4*>(ap + s01*8192 + mr*512); \
  }

#define BUILD(bf, zz)                                                          \
  {                                                                            \
    const int c0 = (int)(((zz) >> (8*(bs*2  ))) & 255u);                       \
    const int c1 = (int)(((zz) >> (8*(bs*2+1))) & 255u);                       \
    int2 g0 = *reinterpret_cast<const int2*>(&tbl[brep + 2*c0]);               \
    int2 g1 = *reinterpret_cast<const int2*>(&tbl[brep + 2*c1]);               \
    i32x4 ch = (i32x4){g0.x, g0.y, g1.x, g1.y};                                \
    *reinterpret_cast<i32x4*>(&Bl[bf][boff]) = ch;                             \
  }

#define COMPUTE(bf, Ad)                                                        \
  {                                                                            \
    i32x4 Bf[2][2];                                                            \
    _Pragma("unroll")                                                          \
    for (int s01 = 0; s01 < 2; ++s01)                                          \
      _Pragma("unroll")                                                        \
      for (int ct = 0; ct < 2; ++ct)                                           \
        Bf[s01][ct] = *reinterpret_cast<const i32x4*>(                         \
            &Bl[bf][roff + s01*2048 + ct*1024]);                               \
    _Pragma("unroll")                                                          \
    for (int s01 = 0; s01 < 2; ++s01)                                          \
      _Pragma("unroll")                                                        \
      for (int ct = 0; ct < 2; ++ct)                                           \
        _Pragma("unroll")                                                      \
        for (int mr = 0; mr < 2; ++mr)                                         \
          acc[mr][ct] = __builtin_amdgcn_mfma_i32_32x32x32_i8(                 \
              Ad[s01][mr], Bf[s01][ct], acc[mr][ct], 0, 0, 0);                 \
  }

  uint2 ztc, ztn;
  i32x4 Aa[2][2], Ab[2][2];

  // ---- prologue ----
  ZLDU(0, ztc);
  ALOADG(0, Aa);
  __syncthreads();             // tbl visible to all waves
  BUILD(0, ztc.x);             // step (0,hf=0) -> buf0
  ZLDU(1, ztn);
  __syncthreads();             // buf0 ready

  for (int u = 0; u < 16; ++u) {
    // step (u,0): compute buf0; build (u,1)->buf1
    ALOADG(2*u + 1, Ab);
    BUILD(1, ztc.y);
    COMPUTE(0, Aa);
    __syncthreads();
    // step (u,1): compute buf1; build (u+1,0)->buf0
    ALOADG(2*u + 2, Aa);
    BUILD(0, ztn.x);
    COMPUTE(1, Ab);
    ztc = ztn;
    ZLDU(u + 2, ztn);
    __syncthreads();
  }
#undef ZLDU
#undef ALOADG
#undef BUILD
#undef COMPUTE

  // ---- fused epilogue: dequant, exp-sum, Z1-selected sum per column m ----
  const float scale = sVbuf[0] * (1.f / 127.f);
#pragma unroll
  for (int ct = 0; ct < 2; ++ct) {
    const int m = m0 + ct*32 + lc;
    float se = 0.f, en = 0.f;
#pragma unroll
    for (int mr = 0; mr < 2; ++mr) {
#pragma unroll
      for (int r = 0; r < 16; ++r) {
        int row = wrow + mr*32 + (r & 3) + 8*(r >> 2) + 4*lo;
        float g = (float)acc[mr][ct][r] * scale;
        se += __expf(g);
        en += (Z1[row*MM + m] == a_blk) ? g : 0.f;
      }
    }
    se += __shfl_xor(se, 32);
    en += __shfl_xor(en, 32);
    if (lo == 0) {
      atomicAdd(&Sexp[m], se);
      atomicAdd(&Ene[m], en);
    }
  }
}

// Kernel 4: pl = -sum_m w[m]*(Ene[m] - log(Sexp[m] + 235)); block 16 adds reg term.
__global__ void k_final(const float* __restrict__ Sexp, const float* __restrict__ Ene,
                        const float* __restrict__ wts, const float* __restrict__ Mmat,
                        const float* __restrict__ Vf, float* __restrict__ out) {
  __shared__ float r4[4];
  float val = 0.f;
  if (blockIdx.x < 16) {
    int m = blockIdx.x * 256 + threadIdx.x;
    val = -wts[m] * (Ene[m] - logf(Sexp[m] + 235.0f));
  } else {
    int t = threadIdx.x;
    if (t < 64) {
      int h = t >> 3, k = t & 7;
      float dot = 0.f;
      for (int x = 0; x < Q1c*Q2c; ++x) dot += Vf[h*(Q1c*Q2c)+x] * Vf[k*(Q1c*Q2c)+x];
      int hh = (h < k) ? h : k;
      int kk = (h < k) ? k : h;
      int idx = hh*8 - (hh*(hh-1))/2 + (kk - hh);   // upper-tri index
      val = 0.001f * Mmat[idx] * dot;               // LAMBD = 0.001
    }
  }
#pragma unroll
  for (int o = 32; o; o >>= 1) val += __shfl_xor(val, o);
  int w = threadIdx.x >> 6;
  if ((threadIdx.x & 63) == 0) r4[w] = val;
  __syncthreads();
  if (threadIdx.x == 0) atomicAdd(out, r4[0] + r4[1] + r4[2] + r4[3]);
}

extern "C" void kernel_launch(void* const* d_in, const int* in_sizes, int n_in,
                              void* d_out, int out_size, void* d_ws, size_t ws_size,
                              hipStream_t stream) {
  const float* Q   = (const float*)d_in[0];
  const float* K   = (const float*)d_in[1];
  const float* V   = (const float*)d_in[2];
  const int*   Z1  = (const int*)d_in[3];
  const int*   Z2  = (const int*)d_in[4];
  const float* wts = (const float*)d_in[5];
  float* out = (float*)d_out;

  char* ws = (char*)d_ws;
  float*          sf   = (float*)ws;                               // 2 MB
  unsigned char*  qsfF = (unsigned char*)(ws + (2u << 20));        // 512 KB
  unsigned char*  Z2t  = (unsigned char*)(ws + (3u << 20));        // 1 MB
  float*          Sexp = (float*)(ws + (4u << 20));                // 16 KB
  float*          Ene  = (float*)(ws + (4u << 20) + (16u << 10));  // 16 KB
  float*          Mmat = (float*)(ws + (4u << 20) + (32u << 10));  // 144 B
  unsigned char*  qVt  = (unsigned char*)(ws + (4u << 20) + (40u << 10)); // 3528 B
  float*          sVbuf= (float*)(ws + (4u << 20) + (48u << 10));  // 4 B

  hipMemsetAsync(out, 0, sizeof(float), stream);
  hipMemsetAsync(ws + (4u << 20), 0, (33u << 10), stream);

  k_combo  <<<dim3(2561), dim3(256), 0, stream>>>(Z2, Z2t, V, qVt, sVbuf, Q, K, sf, qsfF);
  k_mmat   <<<dim3(64),   dim3(256), 0, stream>>>(sf, Mmat);
  k_gemm   <<<dim3(1344), dim3(256), 0, stream>>>(qsfF, qVt, sVbuf, Z1, Z2t, Sexp, Ene);
  k_final  <<<dim3(17),   dim3(256), 0, stream>>>(Sexp, Ene, wts, Mmat, V, out);
}